// Round 2
// baseline (785.307 us; speedup 1.0000x reference)
//
#include <hip/hip_runtime.h>
#include <hip/hip_bf16.h>

#define N_NODES 100000
#define N_EDGES 1600000
#define DIM 128
#define SCAN_CHUNK 1024

typedef __attribute__((ext_vector_type(8))) short bf16x8;
typedef __attribute__((ext_vector_type(4))) float f32x4;

__global__ void convw_kernel(const float* __restrict__ w1, const float* __restrict__ w2,
                             __hip_bfloat16* __restrict__ w1b, __hip_bfloat16* __restrict__ w2b) {
    int i = blockIdx.x * blockDim.x + threadIdx.x;
    if (i < DIM * DIM) {
        w1b[i] = __float2bfloat16(w1[i]);
        w2b[i] = __float2bfloat16(w2[i]);
    }
}

__global__ void deg_kernel(const int* __restrict__ dst, int* __restrict__ deg) {
    for (int e = blockIdx.x * blockDim.x + threadIdx.x; e < N_EDGES; e += gridDim.x * blockDim.x)
        atomicAdd(&deg[dst[e]], 1);
}

// per-block partial sums over chunks of 1024
__global__ void scan1_kernel(const int* __restrict__ deg, int* __restrict__ bsum) {
    __shared__ int s[256];
    int t = threadIdx.x;
    int base = blockIdx.x * SCAN_CHUNK + t * 4;
    int v = 0;
    for (int k = 0; k < 4; k++) { int i = base + k; if (i < N_NODES) v += deg[i]; }
    s[t] = v;
    __syncthreads();
    for (int off = 128; off > 0; off >>= 1) { if (t < off) s[t] += s[t + off]; __syncthreads(); }
    if (t == 0) bsum[blockIdx.x] = s[0];
}

__global__ void scan2_kernel(const int* __restrict__ bsum, int* __restrict__ bscan,
                             int* __restrict__ row_start, int nb) {
    if (threadIdx.x == 0) {
        int run = 0;
        for (int b = 0; b < nb; b++) { bscan[b] = run; run += bsum[b]; }
        row_start[N_NODES] = run;
    }
}

__global__ void scan3_kernel(const int* __restrict__ deg, const int* __restrict__ bscan,
                             int* __restrict__ row_start) {
    __shared__ int s[256];
    int t = threadIdx.x;
    int base = blockIdx.x * SCAN_CHUNK + t * 4;
    int v[4]; int tot = 0;
    for (int k = 0; k < 4; k++) { int i = base + k; v[k] = (i < N_NODES) ? deg[i] : 0; tot += v[k]; }
    s[t] = tot;
    __syncthreads();
    // inclusive Hillis-Steele scan over thread sums
    for (int off = 1; off < 256; off <<= 1) {
        int a = (t >= off) ? s[t - off] : 0;
        __syncthreads();
        s[t] += a;
        __syncthreads();
    }
    int run = s[t] - tot + bscan[blockIdx.x];  // exclusive prefix for this thread
    for (int k = 0; k < 4; k++) {
        int i = base + k;
        if (i < N_NODES) row_start[i] = run;
        run += v[k];
    }
}

__global__ void fill_kernel(const int* __restrict__ src, const int* __restrict__ dst,
                            const float* __restrict__ ew, const int* __restrict__ row_start,
                            int* __restrict__ cursor, int* __restrict__ src_s,
                            float* __restrict__ w_s) {
    for (int e = blockIdx.x * blockDim.x + threadIdx.x; e < N_EDGES; e += gridDim.x * blockDim.x) {
        int d_ = dst[e];
        int p = atomicAdd(&cursor[d_], 1);
        int idx = row_start[d_] + p;
        src_s[idx] = src[e];
        w_s[idx] = ew[e];
    }
}

// one block per node, one thread per channel; CSR mean-aggregate + self term, write bf16 h
__global__ void agg_kernel(const float* __restrict__ x, const int* __restrict__ row_start,
                           const int* __restrict__ src_s, const float* __restrict__ w_s,
                           const float* __restrict__ eps, int li, __hip_bfloat16* __restrict__ h) {
    __shared__ int s_s[128];
    __shared__ float s_w[128];
    int n = blockIdx.x;
    int d = threadIdx.x;
    int beg = row_start[n], end = row_start[n + 1];
    float acc = 0.f;
    for (int base = beg; base < end; base += 128) {
        int cnt = min(128, end - base);
        if (d < cnt) { s_s[d] = src_s[base + d]; s_w[d] = w_s[base + d]; }
        __syncthreads();
        int i = 0;
        for (; i + 4 <= cnt; i += 4) {
            float x0 = x[(size_t)s_s[i] * DIM + d];
            float x1 = x[(size_t)s_s[i + 1] * DIM + d];
            float x2 = x[(size_t)s_s[i + 2] * DIM + d];
            float x3 = x[(size_t)s_s[i + 3] * DIM + d];
            acc += x0 * s_w[i] + x1 * s_w[i + 1] + x2 * s_w[i + 2] + x3 * s_w[i + 3];
        }
        for (; i < cnt; i++) acc += x[(size_t)s_s[i] * DIM + d] * s_w[i];
        __syncthreads();
    }
    int degn = end - beg;
    float dinv = degn > 0 ? 1.0f / (float)degn : 0.0f;
    float val = (1.0f + eps[li]) * x[(size_t)n * DIM + d] + acc * dinv;
    h[(size_t)n * DIM + d] = __float2bfloat16(val);
}

// out[n][j] = sum_d h[n][d] * W[j][d] + b[j]; optional relu; optional zero row 0
// block = 4 waves; wave handles 16 rows x 128 cols, K=128
__global__ __launch_bounds__(256) void gemm_kernel(const __hip_bfloat16* __restrict__ A,
                                                   const __hip_bfloat16* __restrict__ W,
                                                   const float* __restrict__ bias,
                                                   float* __restrict__ out, int relu, int zero0) {
    int wave = threadIdx.x >> 6;
    int lane = threadIdx.x & 63;
    int row0 = blockIdx.x * 64 + wave * 16;
    int lr = lane & 15;   // row within A-tile / row of W
    int kg = lane >> 4;   // k-subgroup (8 elements each)

    int arow = row0 + lr;
    if (arow > N_NODES - 1) arow = N_NODES - 1;
    const short* Ap = (const short*)A + (size_t)arow * DIM + kg * 8;
    bf16x8 a[4];
#pragma unroll
    for (int k = 0; k < 4; k++) a[k] = *(const bf16x8*)(Ap + k * 32);

    f32x4 acc[8];
#pragma unroll
    for (int jt = 0; jt < 8; jt++) {
        const short* Wp = (const short*)W + (size_t)(jt * 16 + lr) * DIM + kg * 8;
        f32x4 c = {0.f, 0.f, 0.f, 0.f};
#pragma unroll
        for (int k = 0; k < 4; k++) {
            bf16x8 b = *(const bf16x8*)(Wp + k * 32);
            c = __builtin_amdgcn_mfma_f32_16x16x32_bf16(a[k], b, c, 0, 0, 0);
        }
        acc[jt] = c;
    }

    int colb = lane & 15;
    int rb = (lane >> 4) * 4;
#pragma unroll
    for (int jt = 0; jt < 8; jt++) {
        int col = jt * 16 + colb;
        float bv = bias[col];
#pragma unroll
        for (int r = 0; r < 4; r++) {
            int grow = row0 + rb + r;
            if (grow < N_NODES) {
                float v = acc[jt][r] + bv;
                if (relu) v = fmaxf(v, 0.f);
                if (zero0 && grow == 0) v = 0.f;
                out[(size_t)grow * DIM + col] = v;
            }
        }
    }
}

extern "C" void kernel_launch(void* const* d_in, const int* in_sizes, int n_in,
                              void* d_out, int out_size, void* d_ws, size_t ws_size,
                              hipStream_t stream) {
    const float* emb = (const float*)d_in[0];
    const float* w1  = (const float*)d_in[1];
    const float* b1  = (const float*)d_in[2];
    const float* w2  = (const float*)d_in[3];
    const float* b2  = (const float*)d_in[4];
    const float* eps = (const float*)d_in[5];
    const float* ew  = (const float*)d_in[6];
    const int* src   = (const int*)d_in[7];
    const int* dst   = (const int*)d_in[8];
    float* out = (float*)d_out;

    char* base = (char*)d_ws;
    size_t off = 0;
    auto alloc = [&](size_t bytes) -> char* {
        char* p = base + off;
        off += (bytes + 255) & ~(size_t)255;
        return p;
    };
    int* deg            = (int*)alloc((size_t)N_NODES * 4);
    int* row_start      = (int*)alloc((size_t)(N_NODES + 1) * 4);
    int* cursor         = (int*)alloc((size_t)N_NODES * 4);
    int* bsum           = (int*)alloc(128 * 4);
    int* bscan          = (int*)alloc(128 * 4);
    int* src_s          = (int*)alloc((size_t)N_EDGES * 4);
    float* w_s          = (float*)alloc((size_t)N_EDGES * 4);
    __hip_bfloat16* h   = (__hip_bfloat16*)alloc((size_t)N_NODES * DIM * 2);
    float* xbuf         = (float*)alloc((size_t)N_NODES * DIM * 4);
    __hip_bfloat16* w1b = (__hip_bfloat16*)alloc(DIM * DIM * 2);
    __hip_bfloat16* w2b = (__hip_bfloat16*)alloc(DIM * DIM * 2);

    hipMemsetAsync(deg, 0, (size_t)N_NODES * 4, stream);
    hipMemsetAsync(cursor, 0, (size_t)N_NODES * 4, stream);

    convw_kernel<<<(DIM * DIM + 255) / 256, 256, 0, stream>>>(w1, w2, w1b, w2b);
    deg_kernel<<<1024, 256, 0, stream>>>(dst, deg);

    int nb = (N_NODES + SCAN_CHUNK - 1) / SCAN_CHUNK;
    scan1_kernel<<<nb, 256, 0, stream>>>(deg, bsum);
    scan2_kernel<<<1, 64, 0, stream>>>(bsum, bscan, row_start, nb);
    scan3_kernel<<<nb, 256, 0, stream>>>(deg, bscan, row_start);
    fill_kernel<<<1024, 256, 0, stream>>>(src, dst, ew, row_start, cursor, src_s, w_s);

    int gemm_blocks = (N_NODES + 63) / 64;
    agg_kernel<<<N_NODES, 128, 0, stream>>>(emb, row_start, src_s, w_s, eps, 0, h);
    gemm_kernel<<<gemm_blocks, 256, 0, stream>>>(h, w1b, b1, xbuf, 1, 0);
    agg_kernel<<<N_NODES, 128, 0, stream>>>(xbuf, row_start, src_s, w_s, eps, 1, h);
    gemm_kernel<<<gemm_blocks, 256, 0, stream>>>(h, w2b, b2, xbuf, 1, 0);
    agg_kernel<<<N_NODES, 128, 0, stream>>>(xbuf, row_start, src_s, w_s, eps, 2, h);
    gemm_kernel<<<gemm_blocks, 256, 0, stream>>>(h, w2b, b2, out, 0, 1);
}

// Round 3
// 671.217 us; speedup vs baseline: 1.1700x; 1.1700x over previous
//
#include <hip/hip_runtime.h>
#include <hip/hip_bf16.h>

#define N_NODES 100000
#define N_EDGES 1600000
#define DIM 128
#define SCAN_CHUNK 1024

typedef __attribute__((ext_vector_type(8))) short bf16x8;
typedef __attribute__((ext_vector_type(4))) float f32x4;
typedef __attribute__((ext_vector_type(4))) short bf16x4;

// fp32 -> bf16 elementwise (RNE), 4 elems/thread
__global__ void cvt_kernel(const float* __restrict__ in, __hip_bfloat16* __restrict__ out, int n4) {
    int i = blockIdx.x * blockDim.x + threadIdx.x;
    if (i < n4) {
        f32x4 v = ((const f32x4*)in)[i];
        bf16x4 o;
        o.x = (short)__bfloat16_as_ushort(__float2bfloat16(v.x));
        o.y = (short)__bfloat16_as_ushort(__float2bfloat16(v.y));
        o.z = (short)__bfloat16_as_ushort(__float2bfloat16(v.z));
        o.w = (short)__bfloat16_as_ushort(__float2bfloat16(v.w));
        ((bf16x4*)out)[i] = o;
    }
}

__global__ void deg_kernel(const int* __restrict__ dst, int* __restrict__ deg) {
    for (int e = blockIdx.x * blockDim.x + threadIdx.x; e < N_EDGES; e += gridDim.x * blockDim.x)
        atomicAdd(&deg[dst[e]], 1);
}

// per-block partial sums over chunks of 1024
__global__ void scan1_kernel(const int* __restrict__ deg, int* __restrict__ bsum) {
    __shared__ int s[256];
    int t = threadIdx.x;
    int base = blockIdx.x * SCAN_CHUNK + t * 4;
    int v = 0;
    for (int k = 0; k < 4; k++) { int i = base + k; if (i < N_NODES) v += deg[i]; }
    s[t] = v;
    __syncthreads();
    for (int off = 128; off > 0; off >>= 1) { if (t < off) s[t] += s[t + off]; __syncthreads(); }
    if (t == 0) bsum[blockIdx.x] = s[0];
}

__global__ void scan2_kernel(const int* __restrict__ bsum, int* __restrict__ bscan,
                             int* __restrict__ row_start, int nb) {
    if (threadIdx.x == 0) {
        int run = 0;
        for (int b = 0; b < nb; b++) { bscan[b] = run; run += bsum[b]; }
        row_start[N_NODES] = run;
    }
}

// writes row_start AND initializes cursor to row_start
__global__ void scan3_kernel(const int* __restrict__ deg, const int* __restrict__ bscan,
                             int* __restrict__ row_start, int* __restrict__ cursor) {
    __shared__ int s[256];
    int t = threadIdx.x;
    int base = blockIdx.x * SCAN_CHUNK + t * 4;
    int v[4]; int tot = 0;
    for (int k = 0; k < 4; k++) { int i = base + k; v[k] = (i < N_NODES) ? deg[i] : 0; tot += v[k]; }
    s[t] = tot;
    __syncthreads();
    for (int off = 1; off < 256; off <<= 1) {
        int a = (t >= off) ? s[t - off] : 0;
        __syncthreads();
        s[t] += a;
        __syncthreads();
    }
    int run = s[t] - tot + bscan[blockIdx.x];  // exclusive prefix for this thread
    for (int k = 0; k < 4; k++) {
        int i = base + k;
        if (i < N_NODES) { row_start[i] = run; cursor[i] = run; }
        run += v[k];
    }
}

// one 8-byte scattered store per edge: (src, edge_w bits)
__global__ void fill_kernel(const int* __restrict__ src, const int* __restrict__ dst,
                            const float* __restrict__ ew, int* __restrict__ cursor,
                            int2* __restrict__ sw_s) {
    for (int e = blockIdx.x * blockDim.x + threadIdx.x; e < N_EDGES; e += gridDim.x * blockDim.x) {
        int d_ = dst[e];
        int idx = atomicAdd(&cursor[d_], 1);
        sw_s[idx] = make_int2(src[e], __float_as_int(ew[e]));
    }
}

// one block (128 thr) per node: CSR mean-aggregate over bf16 x + self term, write bf16 h
__global__ void agg_kernel(const __hip_bfloat16* __restrict__ x, const int* __restrict__ row_start,
                           const int2* __restrict__ sw_s, const float* __restrict__ eps, int li,
                           __hip_bfloat16* __restrict__ h) {
    __shared__ int2 s_sw[128];
    int n = blockIdx.x;
    int d = threadIdx.x;
    int beg = row_start[n], end = row_start[n + 1];
    float acc = 0.f;
    for (int base = beg; base < end; base += 128) {
        int cnt = min(128, end - base);
        if (d < cnt) s_sw[d] = sw_s[base + d];
        __syncthreads();
        int i = 0;
        for (; i + 4 <= cnt; i += 4) {
            int2 e0 = s_sw[i], e1 = s_sw[i + 1], e2 = s_sw[i + 2], e3 = s_sw[i + 3];
            acc += __bfloat162float(x[(size_t)e0.x * DIM + d]) * __int_as_float(e0.y)
                 + __bfloat162float(x[(size_t)e1.x * DIM + d]) * __int_as_float(e1.y)
                 + __bfloat162float(x[(size_t)e2.x * DIM + d]) * __int_as_float(e2.y)
                 + __bfloat162float(x[(size_t)e3.x * DIM + d]) * __int_as_float(e3.y);
        }
        for (; i < cnt; i++)
            acc += __bfloat162float(x[(size_t)s_sw[i].x * DIM + d]) * __int_as_float(s_sw[i].y);
        __syncthreads();
    }
    int degn = end - beg;
    float dinv = degn > 0 ? 1.0f / (float)degn : 0.0f;
    float val = (1.0f + eps[li]) * __bfloat162float(x[(size_t)n * DIM + d]) + acc * dinv;
    h[(size_t)n * DIM + d] = __float2bfloat16(val);
}

// out[n][j] = sum_d h[n][d] * W[j][d] + b[j]; optional relu / zero row0 / bf16-or-fp32 out.
// block = 4 waves; wave handles 16 rows x 128 cols, K=128
template <int RELU, int ZERO0, int OUTBF>
__global__ __launch_bounds__(256) void gemm_kernel(const __hip_bfloat16* __restrict__ A,
                                                   const __hip_bfloat16* __restrict__ W,
                                                   const float* __restrict__ bias,
                                                   void* __restrict__ outv) {
    int wave = threadIdx.x >> 6;
    int lane = threadIdx.x & 63;
    int row0 = blockIdx.x * 64 + wave * 16;
    int lr = lane & 15;   // row within A-tile / row of W
    int kg = lane >> 4;   // k-subgroup (8 elements each)

    int arow = row0 + lr;
    if (arow > N_NODES - 1) arow = N_NODES - 1;
    const short* Ap = (const short*)A + (size_t)arow * DIM + kg * 8;
    bf16x8 a[4];
#pragma unroll
    for (int k = 0; k < 4; k++) a[k] = *(const bf16x8*)(Ap + k * 32);

    f32x4 acc[8];
#pragma unroll
    for (int jt = 0; jt < 8; jt++) {
        const short* Wp = (const short*)W + (size_t)(jt * 16 + lr) * DIM + kg * 8;
        f32x4 c = {0.f, 0.f, 0.f, 0.f};
#pragma unroll
        for (int k = 0; k < 4; k++) {
            bf16x8 b = *(const bf16x8*)(Wp + k * 32);
            c = __builtin_amdgcn_mfma_f32_16x16x32_bf16(a[k], b, c, 0, 0, 0);
        }
        acc[jt] = c;
    }

    int colb = lane & 15;
    int rb = (lane >> 4) * 4;
#pragma unroll
    for (int jt = 0; jt < 8; jt++) {
        int col = jt * 16 + colb;
        float bv = bias[col];
#pragma unroll
        for (int r = 0; r < 4; r++) {
            int grow = row0 + rb + r;
            if (grow < N_NODES) {
                float v = acc[jt][r] + bv;
                if (RELU) v = fmaxf(v, 0.f);
                if (ZERO0 && grow == 0) v = 0.f;
                if (OUTBF)
                    ((__hip_bfloat16*)outv)[(size_t)grow * DIM + col] = __float2bfloat16(v);
                else
                    ((float*)outv)[(size_t)grow * DIM + col] = v;
            }
        }
    }
}

extern "C" void kernel_launch(void* const* d_in, const int* in_sizes, int n_in,
                              void* d_out, int out_size, void* d_ws, size_t ws_size,
                              hipStream_t stream) {
    const float* emb = (const float*)d_in[0];
    const float* w1  = (const float*)d_in[1];
    const float* b1  = (const float*)d_in[2];
    const float* w2  = (const float*)d_in[3];
    const float* b2  = (const float*)d_in[4];
    const float* eps = (const float*)d_in[5];
    const float* ew  = (const float*)d_in[6];
    const int* src   = (const int*)d_in[7];
    const int* dst   = (const int*)d_in[8];
    float* out = (float*)d_out;

    char* base = (char*)d_ws;
    size_t off = 0;
    auto alloc = [&](size_t bytes) -> char* {
        char* p = base + off;
        off += (bytes + 255) & ~(size_t)255;
        return p;
    };
    int* deg            = (int*)alloc((size_t)N_NODES * 4);
    int* row_start      = (int*)alloc((size_t)(N_NODES + 1) * 4);
    int* cursor         = (int*)alloc((size_t)N_NODES * 4);
    int* bsum           = (int*)alloc(128 * 4);
    int* bscan          = (int*)alloc(128 * 4);
    int2* sw_s          = (int2*)alloc((size_t)N_EDGES * 8);
    __hip_bfloat16* h   = (__hip_bfloat16*)alloc((size_t)N_NODES * DIM * 2);
    __hip_bfloat16* xb  = (__hip_bfloat16*)alloc((size_t)N_NODES * DIM * 2);
    __hip_bfloat16* embb= (__hip_bfloat16*)alloc((size_t)N_NODES * DIM * 2);
    __hip_bfloat16* w1b = (__hip_bfloat16*)alloc(DIM * DIM * 2);
    __hip_bfloat16* w2b = (__hip_bfloat16*)alloc(DIM * DIM * 2);

    hipMemsetAsync(deg, 0, (size_t)N_NODES * 4, stream);

    // dtype conversions
    cvt_kernel<<<(N_NODES * DIM / 4 + 255) / 256, 256, 0, stream>>>(emb, embb, N_NODES * DIM / 4);
    cvt_kernel<<<(DIM * DIM / 4 + 255) / 256, 256, 0, stream>>>(w1, w1b, DIM * DIM / 4);
    cvt_kernel<<<(DIM * DIM / 4 + 255) / 256, 256, 0, stream>>>(w2, w2b, DIM * DIM / 4);

    // CSR build
    deg_kernel<<<1024, 256, 0, stream>>>(dst, deg);
    int nb = (N_NODES + SCAN_CHUNK - 1) / SCAN_CHUNK;
    scan1_kernel<<<nb, 256, 0, stream>>>(deg, bsum);
    scan2_kernel<<<1, 64, 0, stream>>>(bsum, bscan, row_start, nb);
    scan3_kernel<<<nb, 256, 0, stream>>>(deg, bscan, row_start, cursor);
    fill_kernel<<<1024, 256, 0, stream>>>(src, dst, ew, cursor, sw_s);

    int gemm_blocks = (N_NODES + 63) / 64;
    agg_kernel<<<N_NODES, 128, 0, stream>>>(embb, row_start, sw_s, eps, 0, h);
    gemm_kernel<1, 0, 1><<<gemm_blocks, 256, 0, stream>>>(h, w1b, b1, xb);
    agg_kernel<<<N_NODES, 128, 0, stream>>>(xb, row_start, sw_s, eps, 1, h);
    gemm_kernel<1, 0, 1><<<gemm_blocks, 256, 0, stream>>>(h, w2b, b2, xb);
    agg_kernel<<<N_NODES, 128, 0, stream>>>(xb, row_start, sw_s, eps, 2, h);
    gemm_kernel<0, 1, 0><<<gemm_blocks, 256, 0, stream>>>(h, w2b, b2, out);
}

// Round 4
// 638.730 us; speedup vs baseline: 1.2295x; 1.0509x over previous
//
#include <hip/hip_runtime.h>
#include <hip/hip_bf16.h>

#define N_NODES 100000
#define N_EDGES 1600000
#define DIM 128
#define SCAN_CHUNK 1024

typedef __attribute__((ext_vector_type(8))) short bf16x8;
typedef __attribute__((ext_vector_type(4))) float f32x4;
typedef __attribute__((ext_vector_type(4))) short bf16x4;

// fp32 -> bf16 elementwise (RNE), 4 elems/thread
__global__ void cvt_kernel(const float* __restrict__ in, __hip_bfloat16* __restrict__ out, int n4) {
    int i = blockIdx.x * blockDim.x + threadIdx.x;
    if (i < n4) {
        f32x4 v = ((const f32x4*)in)[i];
        bf16x4 o;
        o.x = (short)__bfloat16_as_ushort(__float2bfloat16(v.x));
        o.y = (short)__bfloat16_as_ushort(__float2bfloat16(v.y));
        o.z = (short)__bfloat16_as_ushort(__float2bfloat16(v.z));
        o.w = (short)__bfloat16_as_ushort(__float2bfloat16(v.w));
        ((bf16x4*)out)[i] = o;
    }
}

// degree count + per-edge within-dst rank (atomic return value, stored coalesced)
__global__ void degrank_kernel(const int* __restrict__ dst, int* __restrict__ deg,
                               int* __restrict__ rank) {
    for (int e = blockIdx.x * blockDim.x + threadIdx.x; e < N_EDGES; e += gridDim.x * blockDim.x)
        rank[e] = atomicAdd(&deg[dst[e]], 1);
}

// per-block partial sums over chunks of 1024
__global__ void scan1_kernel(const int* __restrict__ deg, int* __restrict__ bsum) {
    __shared__ int s[256];
    int t = threadIdx.x;
    int base = blockIdx.x * SCAN_CHUNK + t * 4;
    int v = 0;
    for (int k = 0; k < 4; k++) { int i = base + k; if (i < N_NODES) v += deg[i]; }
    s[t] = v;
    __syncthreads();
    for (int off = 128; off > 0; off >>= 1) { if (t < off) s[t] += s[t + off]; __syncthreads(); }
    if (t == 0) bsum[blockIdx.x] = s[0];
}

__global__ void scan2_kernel(const int* __restrict__ bsum, int* __restrict__ bscan,
                             int* __restrict__ row_start, int nb) {
    if (threadIdx.x == 0) {
        int run = 0;
        for (int b = 0; b < nb; b++) { bscan[b] = run; run += bsum[b]; }
        row_start[N_NODES] = run;
    }
}

__global__ void scan3_kernel(const int* __restrict__ deg, const int* __restrict__ bscan,
                             int* __restrict__ row_start) {
    __shared__ int s[256];
    int t = threadIdx.x;
    int base = blockIdx.x * SCAN_CHUNK + t * 4;
    int v[4]; int tot = 0;
    for (int k = 0; k < 4; k++) { int i = base + k; v[k] = (i < N_NODES) ? deg[i] : 0; tot += v[k]; }
    s[t] = tot;
    __syncthreads();
    for (int off = 1; off < 256; off <<= 1) {
        int a = (t >= off) ? s[t - off] : 0;
        __syncthreads();
        s[t] += a;
        __syncthreads();
    }
    int run = s[t] - tot + bscan[blockIdx.x];  // exclusive prefix for this thread
    for (int k = 0; k < 4; k++) {
        int i = base + k;
        if (i < N_NODES) row_start[i] = run;
        run += v[k];
    }
}

// atomic-free scatter: idx = row_start[dst] + rank; one fire-and-forget 8B store per edge
__global__ void fill_kernel(const int* __restrict__ src, const int* __restrict__ dst,
                            const float* __restrict__ ew, const int* __restrict__ rank,
                            const int* __restrict__ row_start, int2* __restrict__ sw_s) {
    for (int e = blockIdx.x * blockDim.x + threadIdx.x; e < N_EDGES; e += gridDim.x * blockDim.x) {
        int idx = row_start[dst[e]] + rank[e];
        sw_s[idx] = make_int2(src[e], __float_as_int(ew[e]));
    }
}

// one block (128 thr) per node: CSR mean-aggregate over bf16 x + self term, write bf16 h
__global__ void agg_kernel(const __hip_bfloat16* __restrict__ x, const int* __restrict__ row_start,
                           const int2* __restrict__ sw_s, const float* __restrict__ eps, int li,
                           __hip_bfloat16* __restrict__ h) {
    __shared__ int2 s_sw[128];
    int n = blockIdx.x;
    int d = threadIdx.x;
    int beg = row_start[n], end = row_start[n + 1];
    float acc = 0.f;
    for (int base = beg; base < end; base += 128) {
        int cnt = min(128, end - base);
        if (d < cnt) s_sw[d] = sw_s[base + d];
        __syncthreads();
        int i = 0;
        for (; i + 4 <= cnt; i += 4) {
            int2 e0 = s_sw[i], e1 = s_sw[i + 1], e2 = s_sw[i + 2], e3 = s_sw[i + 3];
            acc += __bfloat162float(x[(size_t)e0.x * DIM + d]) * __int_as_float(e0.y)
                 + __bfloat162float(x[(size_t)e1.x * DIM + d]) * __int_as_float(e1.y)
                 + __bfloat162float(x[(size_t)e2.x * DIM + d]) * __int_as_float(e2.y)
                 + __bfloat162float(x[(size_t)e3.x * DIM + d]) * __int_as_float(e3.y);
        }
        for (; i < cnt; i++)
            acc += __bfloat162float(x[(size_t)s_sw[i].x * DIM + d]) * __int_as_float(s_sw[i].y);
        __syncthreads();
    }
    int degn = end - beg;
    float dinv = degn > 0 ? 1.0f / (float)degn : 0.0f;
    float val = (1.0f + eps[li]) * __bfloat162float(x[(size_t)n * DIM + d]) + acc * dinv;
    h[(size_t)n * DIM + d] = __float2bfloat16(val);
}

// out[n][j] = sum_d h[n][d] * W[j][d] + b[j]; optional relu / zero row0 / bf16-or-fp32 out.
// block = 4 waves; wave handles 16 rows x 128 cols, K=128
template <int RELU, int ZERO0, int OUTBF>
__global__ __launch_bounds__(256) void gemm_kernel(const __hip_bfloat16* __restrict__ A,
                                                   const __hip_bfloat16* __restrict__ W,
                                                   const float* __restrict__ bias,
                                                   void* __restrict__ outv) {
    int wave = threadIdx.x >> 6;
    int lane = threadIdx.x & 63;
    int row0 = blockIdx.x * 64 + wave * 16;
    int lr = lane & 15;   // row within A-tile / row of W
    int kg = lane >> 4;   // k-subgroup (8 elements each)

    int arow = row0 + lr;
    if (arow > N_NODES - 1) arow = N_NODES - 1;
    const short* Ap = (const short*)A + (size_t)arow * DIM + kg * 8;
    bf16x8 a[4];
#pragma unroll
    for (int k = 0; k < 4; k++) a[k] = *(const bf16x8*)(Ap + k * 32);

    f32x4 acc[8];
#pragma unroll
    for (int jt = 0; jt < 8; jt++) {
        const short* Wp = (const short*)W + (size_t)(jt * 16 + lr) * DIM + kg * 8;
        f32x4 c = {0.f, 0.f, 0.f, 0.f};
#pragma unroll
        for (int k = 0; k < 4; k++) {
            bf16x8 b = *(const bf16x8*)(Wp + k * 32);
            c = __builtin_amdgcn_mfma_f32_16x16x32_bf16(a[k], b, c, 0, 0, 0);
        }
        acc[jt] = c;
    }

    int colb = lane & 15;
    int rb = (lane >> 4) * 4;
#pragma unroll
    for (int jt = 0; jt < 8; jt++) {
        int col = jt * 16 + colb;
        float bv = bias[col];
#pragma unroll
        for (int r = 0; r < 4; r++) {
            int grow = row0 + rb + r;
            if (grow < N_NODES) {
                float v = acc[jt][r] + bv;
                if (RELU) v = fmaxf(v, 0.f);
                if (ZERO0 && grow == 0) v = 0.f;
                if (OUTBF)
                    ((__hip_bfloat16*)outv)[(size_t)grow * DIM + col] = __float2bfloat16(v);
                else
                    ((float*)outv)[(size_t)grow * DIM + col] = v;
            }
        }
    }
}

extern "C" void kernel_launch(void* const* d_in, const int* in_sizes, int n_in,
                              void* d_out, int out_size, void* d_ws, size_t ws_size,
                              hipStream_t stream) {
    const float* emb = (const float*)d_in[0];
    const float* w1  = (const float*)d_in[1];
    const float* b1  = (const float*)d_in[2];
    const float* w2  = (const float*)d_in[3];
    const float* b2  = (const float*)d_in[4];
    const float* eps = (const float*)d_in[5];
    const float* ew  = (const float*)d_in[6];
    const int* src   = (const int*)d_in[7];
    const int* dst   = (const int*)d_in[8];
    float* out = (float*)d_out;

    char* base = (char*)d_ws;
    size_t off = 0;
    auto alloc = [&](size_t bytes) -> char* {
        char* p = base + off;
        off += (bytes + 255) & ~(size_t)255;
        return p;
    };
    int* deg            = (int*)alloc((size_t)N_NODES * 4);
    int* row_start      = (int*)alloc((size_t)(N_NODES + 1) * 4);
    int* rank           = (int*)alloc((size_t)N_EDGES * 4);
    int* bsum           = (int*)alloc(128 * 4);
    int* bscan          = (int*)alloc(128 * 4);
    int2* sw_s          = (int2*)alloc((size_t)N_EDGES * 8);
    __hip_bfloat16* h   = (__hip_bfloat16*)alloc((size_t)N_NODES * DIM * 2);
    __hip_bfloat16* xb  = (__hip_bfloat16*)alloc((size_t)N_NODES * DIM * 2);
    __hip_bfloat16* embb= (__hip_bfloat16*)alloc((size_t)N_NODES * DIM * 2);
    __hip_bfloat16* w1b = (__hip_bfloat16*)alloc(DIM * DIM * 2);
    __hip_bfloat16* w2b = (__hip_bfloat16*)alloc(DIM * DIM * 2);

    hipMemsetAsync(deg, 0, (size_t)N_NODES * 4, stream);

    // dtype conversions
    cvt_kernel<<<(N_NODES * DIM / 4 + 255) / 256, 256, 0, stream>>>(emb, embb, N_NODES * DIM / 4);
    cvt_kernel<<<(DIM * DIM / 4 + 255) / 256, 256, 0, stream>>>(w1, w1b, DIM * DIM / 4);
    cvt_kernel<<<(DIM * DIM / 4 + 255) / 256, 256, 0, stream>>>(w2, w2b, DIM * DIM / 4);

    // CSR build (atomic-free scatter via precomputed ranks)
    degrank_kernel<<<2048, 256, 0, stream>>>(dst, deg, rank);
    int nb = (N_NODES + SCAN_CHUNK - 1) / SCAN_CHUNK;
    scan1_kernel<<<nb, 256, 0, stream>>>(deg, bsum);
    scan2_kernel<<<1, 64, 0, stream>>>(bsum, bscan, row_start, nb);
    scan3_kernel<<<nb, 256, 0, stream>>>(deg, bscan, row_start);
    fill_kernel<<<2048, 256, 0, stream>>>(src, dst, ew, rank, row_start, sw_s);

    int gemm_blocks = (N_NODES + 63) / 64;
    agg_kernel<<<N_NODES, 128, 0, stream>>>(embb, row_start, sw_s, eps, 0, h);
    gemm_kernel<1, 0, 1><<<gemm_blocks, 256, 0, stream>>>(h, w1b, b1, xb);
    agg_kernel<<<N_NODES, 128, 0, stream>>>(xb, row_start, sw_s, eps, 1, h);
    gemm_kernel<1, 0, 1><<<gemm_blocks, 256, 0, stream>>>(h, w2b, b2, xb);
    agg_kernel<<<N_NODES, 128, 0, stream>>>(xb, row_start, sw_s, eps, 2, h);
    gemm_kernel<0, 1, 0><<<gemm_blocks, 256, 0, stream>>>(h, w2b, b2, out);
}

// Round 5
// 559.168 us; speedup vs baseline: 1.4044x; 1.1423x over previous
//
#include <hip/hip_runtime.h>
#include <hip/hip_bf16.h>

#define N_NODES 100000
#define N_EDGES 1600000
#define DIM 128
#define SCAN_CHUNK 1024

typedef __attribute__((ext_vector_type(8))) short bf16x8;
typedef __attribute__((ext_vector_type(4))) float f32x4;
typedef __attribute__((ext_vector_type(4))) short bf16x4;

// fp32 -> bf16 elementwise (RNE), 4 elems/thread
__global__ void cvt_kernel(const float* __restrict__ in, __hip_bfloat16* __restrict__ out, int n4) {
    int i = blockIdx.x * blockDim.x + threadIdx.x;
    if (i < n4) {
        f32x4 v = ((const f32x4*)in)[i];
        bf16x4 o;
        o.x = (short)__bfloat16_as_ushort(__float2bfloat16(v.x));
        o.y = (short)__bfloat16_as_ushort(__float2bfloat16(v.y));
        o.z = (short)__bfloat16_as_ushort(__float2bfloat16(v.z));
        o.w = (short)__bfloat16_as_ushort(__float2bfloat16(v.w));
        ((bf16x4*)out)[i] = o;
    }
}

// degree count + per-edge within-dst rank (atomic return value, stored coalesced)
__global__ void degrank_kernel(const int* __restrict__ dst, int* __restrict__ deg,
                               int* __restrict__ rank) {
    for (int e = blockIdx.x * blockDim.x + threadIdx.x; e < N_EDGES; e += gridDim.x * blockDim.x)
        rank[e] = atomicAdd(&deg[dst[e]], 1);
}

// per-block partial sums over chunks of 1024
__global__ void scan1_kernel(const int* __restrict__ deg, int* __restrict__ bsum) {
    __shared__ int s[256];
    int t = threadIdx.x;
    int base = blockIdx.x * SCAN_CHUNK + t * 4;
    int v = 0;
    for (int k = 0; k < 4; k++) { int i = base + k; if (i < N_NODES) v += deg[i]; }
    s[t] = v;
    __syncthreads();
    for (int off = 128; off > 0; off >>= 1) { if (t < off) s[t] += s[t + off]; __syncthreads(); }
    if (t == 0) bsum[blockIdx.x] = s[0];
}

__global__ void scan2_kernel(const int* __restrict__ bsum, int* __restrict__ bscan,
                             int* __restrict__ row_start, int nb) {
    if (threadIdx.x == 0) {
        int run = 0;
        for (int b = 0; b < nb; b++) { bscan[b] = run; run += bsum[b]; }
        row_start[N_NODES] = run;
    }
}

__global__ void scan3_kernel(const int* __restrict__ deg, const int* __restrict__ bscan,
                             int* __restrict__ row_start) {
    __shared__ int s[256];
    int t = threadIdx.x;
    int base = blockIdx.x * SCAN_CHUNK + t * 4;
    int v[4]; int tot = 0;
    for (int k = 0; k < 4; k++) { int i = base + k; v[k] = (i < N_NODES) ? deg[i] : 0; tot += v[k]; }
    s[t] = tot;
    __syncthreads();
    for (int off = 1; off < 256; off <<= 1) {
        int a = (t >= off) ? s[t - off] : 0;
        __syncthreads();
        s[t] += a;
        __syncthreads();
    }
    int run = s[t] - tot + bscan[blockIdx.x];  // exclusive prefix for this thread
    for (int k = 0; k < 4; k++) {
        int i = base + k;
        if (i < N_NODES) row_start[i] = run;
        run += v[k];
    }
}

// atomic-free scatter: idx = row_start[dst] + rank; one fire-and-forget 8B store per edge
__global__ void fill_kernel(const int* __restrict__ src, const int* __restrict__ dst,
                            const float* __restrict__ ew, const int* __restrict__ rank,
                            const int* __restrict__ row_start, int2* __restrict__ sw_s) {
    for (int e = blockIdx.x * blockDim.x + threadIdx.x; e < N_EDGES; e += gridDim.x * blockDim.x) {
        int idx = row_start[dst[e]] + rank[e];
        sw_s[idx] = make_int2(src[e], __float_as_int(ew[e]));
    }
}

// one WAVE per node (4 nodes / 256-thr block); each lane owns 2 adjacent channels
// (bf16x2 = 4B gather per lane -> 256B/wave transaction). Wave-synchronous LDS
// staging: no __syncthreads (waves have independent, divergent degree loops).
__global__ __launch_bounds__(256) void agg_kernel(const __hip_bfloat16* __restrict__ x,
                                                  const int* __restrict__ row_start,
                                                  const int2* __restrict__ sw_s,
                                                  const float* __restrict__ eps, int li,
                                                  __hip_bfloat16* __restrict__ h) {
    __shared__ int2 s_sw[4][64];
    int wv = threadIdx.x >> 6;
    int lane = threadIdx.x & 63;
    int n = blockIdx.x * 4 + wv;
    if (n >= N_NODES) return;
    int beg = row_start[n], end = row_start[n + 1];
    const __hip_bfloat162* xp = (const __hip_bfloat162*)x;  // row n: 64 x bf16x2
    float ax = 0.f, ay = 0.f;
    for (int base = beg; base < end; base += 64) {
        int cnt = min(64, end - base);
        if (lane < cnt) s_sw[wv][lane] = sw_s[base + lane];
        // wave-synchronous: ds_write completed for all 64 lockstep lanes before reads
        asm volatile("s_waitcnt lgkmcnt(0)" ::: "memory");
        int i = 0;
        for (; i + 4 <= cnt; i += 4) {
            int2 e0 = s_sw[wv][i], e1 = s_sw[wv][i + 1], e2 = s_sw[wv][i + 2], e3 = s_sw[wv][i + 3];
            __hip_bfloat162 v0 = xp[(size_t)e0.x * 64 + lane];
            __hip_bfloat162 v1 = xp[(size_t)e1.x * 64 + lane];
            __hip_bfloat162 v2 = xp[(size_t)e2.x * 64 + lane];
            __hip_bfloat162 v3 = xp[(size_t)e3.x * 64 + lane];
            float w0 = __int_as_float(e0.y), w1 = __int_as_float(e1.y);
            float w2 = __int_as_float(e2.y), w3 = __int_as_float(e3.y);
            ax += __bfloat162float(v0.x) * w0 + __bfloat162float(v1.x) * w1
                + __bfloat162float(v2.x) * w2 + __bfloat162float(v3.x) * w3;
            ay += __bfloat162float(v0.y) * w0 + __bfloat162float(v1.y) * w1
                + __bfloat162float(v2.y) * w2 + __bfloat162float(v3.y) * w3;
        }
        for (; i < cnt; i++) {
            int2 e = s_sw[wv][i];
            __hip_bfloat162 v = xp[(size_t)e.x * 64 + lane];
            float w = __int_as_float(e.y);
            ax += __bfloat162float(v.x) * w;
            ay += __bfloat162float(v.y) * w;
        }
        asm volatile("" ::: "memory");  // keep next iter's ds_write below these reads
    }
    int degn = end - beg;
    float dinv = degn > 0 ? 1.0f / (float)degn : 0.0f;
    float ep = 1.0f + eps[li];
    __hip_bfloat162 xs = xp[(size_t)n * 64 + lane];
    float vx = ep * __bfloat162float(xs.x) + ax * dinv;
    float vy = ep * __bfloat162float(xs.y) + ay * dinv;
    __hip_bfloat162 o;
    o.x = __float2bfloat16(vx);
    o.y = __float2bfloat16(vy);
    ((__hip_bfloat162*)h)[(size_t)n * 64 + lane] = o;
}

// out[n][j] = sum_d h[n][d] * W[j][d] + b[j]; optional relu / zero row0 / bf16-or-fp32 out.
// block = 4 waves; wave handles 16 rows x 128 cols, K=128
template <int RELU, int ZERO0, int OUTBF>
__global__ __launch_bounds__(256) void gemm_kernel(const __hip_bfloat16* __restrict__ A,
                                                   const __hip_bfloat16* __restrict__ W,
                                                   const float* __restrict__ bias,
                                                   void* __restrict__ outv) {
    int wave = threadIdx.x >> 6;
    int lane = threadIdx.x & 63;
    int row0 = blockIdx.x * 64 + wave * 16;
    int lr = lane & 15;   // row within A-tile / row of W
    int kg = lane >> 4;   // k-subgroup (8 elements each)

    int arow = row0 + lr;
    if (arow > N_NODES - 1) arow = N_NODES - 1;
    const short* Ap = (const short*)A + (size_t)arow * DIM + kg * 8;
    bf16x8 a[4];
#pragma unroll
    for (int k = 0; k < 4; k++) a[k] = *(const bf16x8*)(Ap + k * 32);

    f32x4 acc[8];
#pragma unroll
    for (int jt = 0; jt < 8; jt++) {
        const short* Wp = (const short*)W + (size_t)(jt * 16 + lr) * DIM + kg * 8;
        f32x4 c = {0.f, 0.f, 0.f, 0.f};
#pragma unroll
        for (int k = 0; k < 4; k++) {
            bf16x8 b = *(const bf16x8*)(Wp + k * 32);
            c = __builtin_amdgcn_mfma_f32_16x16x32_bf16(a[k], b, c, 0, 0, 0);
        }
        acc[jt] = c;
    }

    int colb = lane & 15;
    int rb = (lane >> 4) * 4;
#pragma unroll
    for (int jt = 0; jt < 8; jt++) {
        int col = jt * 16 + colb;
        float bv = bias[col];
#pragma unroll
        for (int r = 0; r < 4; r++) {
            int grow = row0 + rb + r;
            if (grow < N_NODES) {
                float v = acc[jt][r] + bv;
                if (RELU) v = fmaxf(v, 0.f);
                if (ZERO0 && grow == 0) v = 0.f;
                if (OUTBF)
                    ((__hip_bfloat16*)outv)[(size_t)grow * DIM + col] = __float2bfloat16(v);
                else
                    ((float*)outv)[(size_t)grow * DIM + col] = v;
            }
        }
    }
}

extern "C" void kernel_launch(void* const* d_in, const int* in_sizes, int n_in,
                              void* d_out, int out_size, void* d_ws, size_t ws_size,
                              hipStream_t stream) {
    const float* emb = (const float*)d_in[0];
    const float* w1  = (const float*)d_in[1];
    const float* b1  = (const float*)d_in[2];
    const float* w2  = (const float*)d_in[3];
    const float* b2  = (const float*)d_in[4];
    const float* eps = (const float*)d_in[5];
    const float* ew  = (const float*)d_in[6];
    const int* src   = (const int*)d_in[7];
    const int* dst   = (const int*)d_in[8];
    float* out = (float*)d_out;

    char* base = (char*)d_ws;
    size_t off = 0;
    auto alloc = [&](size_t bytes) -> char* {
        char* p = base + off;
        off += (bytes + 255) & ~(size_t)255;
        return p;
    };
    int* deg            = (int*)alloc((size_t)N_NODES * 4);
    int* row_start      = (int*)alloc((size_t)(N_NODES + 1) * 4);
    int* rank           = (int*)alloc((size_t)N_EDGES * 4);
    int* bsum           = (int*)alloc(128 * 4);
    int* bscan          = (int*)alloc(128 * 4);
    int2* sw_s          = (int2*)alloc((size_t)N_EDGES * 8);
    __hip_bfloat16* h   = (__hip_bfloat16*)alloc((size_t)N_NODES * DIM * 2);
    __hip_bfloat16* xb  = (__hip_bfloat16*)alloc((size_t)N_NODES * DIM * 2);
    __hip_bfloat16* embb= (__hip_bfloat16*)alloc((size_t)N_NODES * DIM * 2);
    __hip_bfloat16* w1b = (__hip_bfloat16*)alloc(DIM * DIM * 2);
    __hip_bfloat16* w2b = (__hip_bfloat16*)alloc(DIM * DIM * 2);

    hipMemsetAsync(deg, 0, (size_t)N_NODES * 4, stream);

    // dtype conversions
    cvt_kernel<<<(N_NODES * DIM / 4 + 255) / 256, 256, 0, stream>>>(emb, embb, N_NODES * DIM / 4);
    cvt_kernel<<<(DIM * DIM / 4 + 255) / 256, 256, 0, stream>>>(w1, w1b, DIM * DIM / 4);
    cvt_kernel<<<(DIM * DIM / 4 + 255) / 256, 256, 0, stream>>>(w2, w2b, DIM * DIM / 4);

    // CSR build (atomic-free scatter via precomputed ranks)
    degrank_kernel<<<2048, 256, 0, stream>>>(dst, deg, rank);
    int nb = (N_NODES + SCAN_CHUNK - 1) / SCAN_CHUNK;
    scan1_kernel<<<nb, 256, 0, stream>>>(deg, bsum);
    scan2_kernel<<<1, 64, 0, stream>>>(bsum, bscan, row_start, nb);
    scan3_kernel<<<nb, 256, 0, stream>>>(deg, bscan, row_start);
    fill_kernel<<<2048, 256, 0, stream>>>(src, dst, ew, rank, row_start, sw_s);

    int gemm_blocks = (N_NODES + 63) / 64;
    int agg_blocks = (N_NODES + 3) / 4;
    agg_kernel<<<agg_blocks, 256, 0, stream>>>(embb, row_start, sw_s, eps, 0, h);
    gemm_kernel<1, 0, 1><<<gemm_blocks, 256, 0, stream>>>(h, w1b, b1, xb);
    agg_kernel<<<agg_blocks, 256, 0, stream>>>(xb, row_start, sw_s, eps, 1, h);
    gemm_kernel<1, 0, 1><<<gemm_blocks, 256, 0, stream>>>(h, w2b, b2, xb);
    agg_kernel<<<agg_blocks, 256, 0, stream>>>(xb, row_start, sw_s, eps, 2, h);
    gemm_kernel<0, 1, 0><<<gemm_blocks, 256, 0, stream>>>(h, w2b, b2, out);
}